// Round 8
// baseline (167.712 us; speedup 1.0000x reference)
//
#include <hip/hip_runtime.h>
#include <math.h>

#define JT 64                // j per block (LDS staged)
#define ITILE 1024           // i per block (8 per thread, 128 threads)
#define T8 8                 // 1024-tiles per dimension
#define NJOB_AB 1024         // 8 i-tiles * 128 j-chunks
#define NJOB_TRI 576         // 36 tri-tiles * 16 chunks
#define NBLK (NJOB_AB + 2 * NJOB_TRI)  // 2176
#define NT 128               // threads per pair block (2 waves)
#define L2E 1.4426950408889634f

typedef float v2f __attribute__((ext_vector_type(2)));

// exp2(-x) in ONE instruction: neg folded into VOP3 input modifier.
__device__ inline float fexp2n(float x) {
  float r;
  asm("v_exp_f32 %0, -%1" : "=v"(r) : "v"(x));
  return r;
}
__device__ inline float fsqrt(float x) {
  float r;
  asm("v_sqrt_f32 %0, %1" : "=v"(r) : "v"(x));
  return r;
}

__device__ inline double wred_d(double v) {
#pragma unroll
  for (int o = 32; o > 0; o >>= 1) v += __shfl_down(v, o, 64);
  return v;
}

// block reduction, 256 threads (prep kernel)
__device__ inline double bred256(double v, double* sm) {
  v = wred_d(v);
  __syncthreads();
  if ((threadIdx.x & 63) == 0) sm[threadIdx.x >> 6] = v;
  __syncthreads();
  return sm[0] + sm[1] + sm[2] + sm[3];
}

// block reduction, 128 threads (pair kernel)
__device__ inline double bred128(double v, double* sm) {
  v = wred_d(v);
  __syncthreads();
  if ((threadIdx.x & 63) == 0) sm[threadIdx.x >> 6] = v;
  __syncthreads();
  return sm[0] + sm[1];
}

// wave 0: reduce 64 prep slots -> smean[8] = {Sb,Qb,Mxb,Myb,St,Qt,Mxt,Myt}
__device__ inline void slot_reduce(const double* slot, double* smean) {
  if (threadIdx.x < 64) {
    int l = threadIdx.x;
    const double* sl = slot + l * 4;
#pragma unroll
    for (int c = 0; c < 4; ++c) {
      double v = sl[c];
      double vb = (l < 32) ? v : 0.0;
      double vt = (l < 32) ? 0.0 : v;
      vb = wred_d(vb);
      vt = wred_d(vt);
      if (l == 0) {
        smean[c] = vb;
        smean[4 + c] = vt;
      }
    }
  }
}

__global__ __launch_bounds__(256) void prep_kernel(
    const float* __restrict__ base, const float* __restrict__ target,
    const float* __restrict__ log_sigmas, const float* __restrict__ log_scale,
    const float* __restrict__ w1, const float* __restrict__ b1,
    const float* __restrict__ w2, const float* __restrict__ b2,
    float2* __restrict__ pxy, float* __restrict__ pu,
    double* __restrict__ slot, unsigned* __restrict__ fctr, int n) {
  __shared__ double sm[4];
  int gid = blockIdx.x * 256 + threadIdx.x;
  int isT = gid >= n;  // uniform per block (n % 256 == 0)
  const float* pts = isT ? target : base;
  int idx = isT ? gid - n : gid;
  float ex = __expf(log_scale[0]);
  float ey = __expf(log_scale[1]);
  float s2 = __expf(log_sigmas[2]);
  float r2 = __fsqrt_rn(L2E / (2.f * s2 * s2));  // coord pre-scale, band 2
  float2 p = ((const float2*)pts)[idx];
  float xr = p.x * ex, yr = p.y * ey;  // MLP input space (no r2!)
  float logit = b2[0];
#pragma unroll
  for (int k = 0; k < 32; ++k) {
    float h = fmaf(xr, w1[k], fmaf(yr, w1[32 + k], b1[k]));
    h = fmaxf(h, 0.f);
    logit = fmaf(h, w2[k], logit);
  }
  float u = fmaxf(logit, 0.f) + log1pf(__expf(-fabsf(logit))) + 1e-6f;
  float X = xr * r2, Y = yr * r2;
  pxy[gid] = make_float2(X, Y);
  pu[gid] = u;
  double su = bred256((double)u, sm);
  double qu = bred256((double)u * (double)u, sm);
  double mx = bred256((double)u * (double)X, sm);
  double my = bred256((double)u * (double)Y, sm);
  if (threadIdx.x == 0) {
    double* s = slot + blockIdx.x * 4;
    s[0] = su;
    s[1] = qu;
    s[2] = mx;
    s[3] = my;
    if (blockIdx.x == 0) *fctr = 0u;
  }
}

// Packed-FP32 inner loop, 8 i/thread, dot-form distance.
// pos = Ai + Bj - 2*pi.pj  (Ai=|pi|^2 per-i const, Bj=|pj|^2 staged in LDS)
template <bool AB, bool FAST>
__device__ inline void tile_loop(const float* sx, const float* sy,
                                 const float* su, const float* sB,
                                 const float* snb, const float xi2[8],
                                 const float yi2[8], const float Ai[8],
                                 const float al[8], float rr0, float rr1,
                                 v2f a0[8], v2f a1[8], v2f a2[8], float& sdo,
                                 float& sqo) {
  v2f sd2 = {0.f, 0.f};
  v2f sq2 = {0.f, 0.f};
  const v2f vz = {0.f, 0.f};
#pragma unroll 2
  for (int jj = 0; jj < JT / 2; ++jj) {
    v2f xj = *(const v2f*)&sx[2 * jj];
    v2f yj = *(const v2f*)&sy[2 * jj];
    v2f uj = *(const v2f*)&su[2 * jj];
    v2f Bj = *(const v2f*)&sB[2 * jj];
    v2f nbj;
    if constexpr (AB) nbj = *(const v2f*)&snb[2 * jj];
#pragma unroll
    for (int i = 0; i < 8; ++i) {
      v2f c = Bj + Ai[i];
      v2f xi = {xi2[i], xi2[i]};
      v2f yi = {yi2[i], yi2[i]};
      v2f pos = c - xi * xj - yi * yj;  // pk_fma with neg mods
      v2f k2 = {fexp2n(pos.x), fexp2n(pos.y)};
      v2f k0, k1;
      if constexpr (FAST) {
        v2f t = k2 * k2;
        k1 = t * t;  // k2^4  (sigma ratio 1:2)
        v2f t1 = k1 * k1;
        k0 = t1 * t1;  // k2^16 (sigma ratio 1:4)
      } else {
        v2f m1 = pos * rr1;
        v2f m0 = pos * rr0;
        k1 = {fexp2n(m1.x), fexp2n(m1.y)};
        k0 = {fexp2n(m0.x), fexp2n(m0.y)};
      }
      a0[i] += uj * k0;
      a1[i] += uj * k1;
      a2[i] += uj * k2;
      if constexpr (AB) {
        // uncentered scaled d2 = pos + al_i - bj; clamp vs cancellation
        v2f ali = {al[i], al[i]};
        v2f d2u = (pos + ali) + nbj;
        d2u = __builtin_elementwise_max(d2u, vz);
        sq2 += d2u;
        v2f rt = {fsqrt(d2u.x), fsqrt(d2u.y)};
        sd2 += rt;
      }
    }
  }
  sdo = sd2.x + sd2.y;
  sqo = sq2.x + sq2.y;
}

__global__ __launch_bounds__(NT) void pair_kernel(
    const float2* __restrict__ pxy, const float* __restrict__ pu,
    const double* __restrict__ slot, double* __restrict__ paa,
    double* __restrict__ pbb, double* __restrict__ pab,
    double* __restrict__ psd, double* __restrict__ psq,
    unsigned* __restrict__ fctr, const float* __restrict__ log_sigmas,
    const float* __restrict__ g_w1, const float* __restrict__ g_b1,
    const float* __restrict__ g_w2, const float* __restrict__ g_b2,
    const float* __restrict__ bias, float* __restrict__ out, int n) {
  __shared__ __align__(16) float sx[JT];
  __shared__ __align__(16) float sy[JT];
  __shared__ __align__(16) float su[JT];
  __shared__ __align__(16) float sB[JT];
  __shared__ __align__(16) float snb[JT];
  __shared__ double sm[2];
  __shared__ double smean[8];
  __shared__ int lastf;

  int b = blockIdx.x;
  int tid = threadIdx.x;
  int m, it, jt = 0, j0, pidx;
  if (b < NJOB_AB) {  // AB first (heavier), light tri jobs drain last
    m = 2;
    pidx = b;
    it = b >> 7;          // 8 i-tiles
    j0 = (b & 127) * JT;  // 128 j-chunks
  } else {
    int r = b - NJOB_AB;
    m = (r < NJOB_TRI) ? 0 : 1;
    if (m == 1) r -= NJOB_TRI;
    pidx = r;
    int tile = r >> 4;
    int q = r & 15;
    int idx = tile, len = T8;
    it = 0;
    while (idx >= len) {
      idx -= len;
      --len;
      ++it;
    }
    jt = it + idx;
    j0 = jt * ITILE + q * JT;
  }
  const float2* pxyI = pxy + ((m == 1) ? n : 0);
  const float* puI = pu + ((m == 1) ? n : 0);
  const float2* pxyJ = pxy + ((m == 0) ? 0 : n);
  const float* puJ = pu + ((m == 0) ? 0 : n);

  float cx = 0.f, cy = 0.f, cx2 = 0.f, cy2 = 0.f, cc = 0.f;
  if (m == 2) {
    slot_reduce(slot, smean);  // wave 0; consumed after the barrier below
  }

  float s0 = __expf(log_sigmas[0]);
  float s1 = __expf(log_sigmas[1]);
  float s2 = __expf(log_sigmas[2]);
  float rr0 = (s2 * s2) / (s0 * s0);
  float rr1 = (s2 * s2) / (s1 * s1);
  bool fast = (fabsf(rr0 - 16.f) <= 0.016f) && (fabsf(rr1 - 4.f) <= 0.004f);

  if (m == 2) {
    __syncthreads();
    cx = (float)(smean[2] / smean[0] - smean[6] / smean[4]);
    cy = (float)(smean[3] / smean[0] - smean[7] / smean[4]);
    cx2 = 2.f * cx;
    cy2 = 2.f * cy;
    cc = cx * cx + cy * cy;
  }

  if (tid < JT) {
    float2 v = pxyJ[j0 + tid];
    sx[tid] = v.x;
    sy[tid] = v.y;
    su[tid] = puJ[j0 + tid];
    sB[tid] = fmaf(v.x, v.x, v.y * v.y);  // |pj|^2
    if (m == 2) snb[tid] = -fmaf(cx2, v.x, cy2 * v.y);  // -beta_j
  }
  __syncthreads();

  int i0 = it * ITILE + tid;
  float xi2[8], yi2[8], Ai[8], al[8];
#pragma unroll
  for (int i = 0; i < 8; ++i) {
    float2 P = pxyI[i0 + i * NT];
    float xv = P.x, yv = P.y;
    al[i] = 0.f;
    if (m == 2) {  // center i-side; alpha recovers uncentered distance
      xv -= cx;
      yv -= cy;
      al[i] = fmaf(cx2, xv, cy2 * yv) + cc;
    }
    Ai[i] = fmaf(xv, xv, yv * yv);
    xi2[i] = 2.f * xv;
    yi2[i] = 2.f * yv;
  }

  v2f a0[8] = {}, a1[8] = {}, a2[8] = {};
  float sd = 0.f, sq = 0.f;
  if (m == 2) {
    if (fast)
      tile_loop<true, true>(sx, sy, su, sB, snb, xi2, yi2, Ai, al, rr0, rr1,
                            a0, a1, a2, sd, sq);
    else
      tile_loop<true, false>(sx, sy, su, sB, snb, xi2, yi2, Ai, al, rr0, rr1,
                             a0, a1, a2, sd, sq);
  } else {
    if (fast)
      tile_loop<false, true>(sx, sy, su, sB, snb, xi2, yi2, Ai, al, rr0, rr1,
                             a0, a1, a2, sd, sq);
    else
      tile_loop<false, false>(sx, sy, su, sB, snb, xi2, yi2, Ai, al, rr0, rr1,
                              a0, a1, a2, sd, sq);
  }

  double wgt = (m != 2 && jt != it) ? 2.0 : 1.0;  // symmetric off-diag tiles
  double c0 = 0.0, c1 = 0.0, c2 = 0.0;
#pragma unroll
  for (int i = 0; i < 8; ++i) {
    double ui = (double)puI[i0 + i * NT];  // reload: keeps u out of hot regs
    c0 += ui * (double)(a0[i].x + a0[i].y);
    c1 += ui * (double)(a1[i].x + a1[i].y);
    c2 += ui * (double)(a2[i].x + a2[i].y);
  }
  double r0 = bred128(c0, sm) * wgt;
  double r1 = bred128(c1, sm) * wgt;
  double r2d = bred128(c2, sm) * wgt;
  double* prow = (m == 0) ? paa : (m == 1) ? pbb : pab;
  int stride = (m == 2) ? NJOB_AB : NJOB_TRI;
  if (tid == 0) {
    prow[0 * stride + pidx] = r0;
    prow[1 * stride + pidx] = r1;
    prow[2 * stride + pidx] = r2d;
  }
  if (m == 2) {
    double rsd = bred128((double)sd, sm);
    double rsq = bred128((double)sq, sm);
    if (tid == 0) {
      psd[pidx] = rsd;
      psq[pidx] = rsq;
    }
  }

  // ---- last-block final reduction (ticket + device fence) ----
  if (tid == 0) {
    __threadfence();
    unsigned old = atomicAdd(fctr, 1u);
    lastf = (old == NBLK - 1) ? 1 : 0;
  }
  __syncthreads();
  if (!lastf) return;
  __threadfence();

  slot_reduce(slot, smean);
  __syncthreads();
  int t = tid;
  double vaa[3], vbb[3], vab[3];
  for (int s = 0; s < 3; ++s) {
    const double* pa = paa + s * NJOB_TRI;
    const double* pb = pbb + s * NJOB_TRI;
    const double* pc = pab + s * NJOB_AB;
    double va = pa[t] + pa[t + 128] + pa[t + 256] + pa[t + 384] +
                ((t < 64) ? pa[t + 512] : 0.0);
    double vb = pb[t] + pb[t + 128] + pb[t + 256] + pb[t + 384] +
                ((t < 64) ? pb[t + 512] : 0.0);
    double vc = 0.0;
#pragma unroll
    for (int k = 0; k < 8; ++k) vc += pc[t + 128 * k];
    vaa[s] = bred128(va, sm);
    vbb[s] = bred128(vb, sm);
    vab[s] = bred128(vc, sm);
  }
  double sdp = 0.0, sqp = 0.0;
#pragma unroll
  for (int k = 0; k < 8; ++k) {
    sdp += psd[t + 128 * k];
    sqp += psq[t + 128 * k];
  }
  double sdt = bred128(sdp, sm);
  double sqt = bred128(sqp, sm);

  if (tid == 0) {
    double Sb = smean[0], Qb = smean[1], St = smean[4], Qt = smean[5];
    double pband[3];
    for (int s = 0; s < 3; ++s)
      pband[s] = vaa[s] / (Sb * Sb) + vbb[s] / (St * St) -
                 2.0 * vab[s] / (Sb * St);
    double s2d = (double)s2;
    double r2sq = (double)L2E / (2.0 * s2d * s2d);
    double sd_real = sdt / sqrt(r2sq);
    double sq_real = sqt / r2sq;
    double NN = (double)n;
    double NM = NN * NN;
    double mean_d = sd_real / NM;
    double var_d = (sq_real - sd_real * sd_real / NM) / (NM - 1.0);
    double wv = (Qb / (Sb * Sb) - 1.0 / NN) / (NN - 1.0) +
                (Qt / (St * St) - 1.0 / NN) / (NN - 1.0);
    float st[4] = {(float)mean_d, (float)var_d, 0.f, (float)wv};
    float gl[3] = {g_b2[0], g_b2[1], g_b2[2]};
    for (int k = 0; k < 32; ++k) {
      float h = g_b1[k];
      for (int c = 0; c < 4; ++c) h = fmaf(st[c], g_w1[c * 32 + k], h);
      h = fmaxf(h, 0.f);
      for (int s = 0; s < 3; ++s) gl[s] = fmaf(h, g_w2[k * 3 + s], gl[s]);
    }
    float gw[3];
    float gsum = 0.f;
    for (int s = 0; s < 3; ++s) {
      gw[s] = fmaxf(gl[s], 0.f) + log1pf(__expf(-fabsf(gl[s])));
      gsum += gw[s];
    }
    double r = 0.0;
    for (int s = 0; s < 3; ++s) r += (double)(gw[s] / gsum) * pband[s];
    out[0] = (float)(r + (double)bias[0]);
  }
}

extern "C" void kernel_launch(void* const* d_in, const int* in_sizes, int n_in,
                              void* d_out, int out_size, void* d_ws,
                              size_t ws_size, hipStream_t stream) {
  const float* base = (const float*)d_in[0];
  const float* target = (const float*)d_in[1];
  const float* log_sigmas = (const float*)d_in[2];
  const float* log_scale = (const float*)d_in[3];
  const float* wn_w1 = (const float*)d_in[4];
  const float* wn_b1 = (const float*)d_in[5];
  const float* wn_w2 = (const float*)d_in[6];
  const float* wn_b2 = (const float*)d_in[7];
  const float* g_w1 = (const float*)d_in[8];
  const float* g_b1 = (const float*)d_in[9];
  const float* g_w2 = (const float*)d_in[10];
  const float* g_b2 = (const float*)d_in[11];
  const float* bias = (const float*)d_in[12];
  int n = in_sizes[0] / 2;  // 8192

  double* dbase = (double*)d_ws;
  double* slot = dbase;                // 64*4 = 256
  double* paa = dbase + 256;           // 3*576
  double* pbb = paa + 3 * NJOB_TRI;    // 3*576
  double* pab = pbb + 3 * NJOB_TRI;    // 3*1024
  double* psd = pab + 3 * NJOB_AB;     // 1024
  double* psq = psd + NJOB_AB;         // 1024
  double* dend = psq + NJOB_AB;
  float2* pxy = (float2*)dend;         // 2n
  float* pu = (float*)(pxy + 2 * n);   // 2n
  unsigned* fctr = (unsigned*)(pu + 2 * n);

  prep_kernel<<<(2 * n) / 256, 256, 0, stream>>>(
      base, target, log_sigmas, log_scale, wn_w1, wn_b1, wn_w2, wn_b2, pxy, pu,
      slot, fctr, n);
  pair_kernel<<<NBLK, NT, 0, stream>>>(pxy, pu, slot, paa, pbb, pab, psd, psq,
                                       fctr, log_sigmas, g_w1, g_b1, g_w2,
                                       g_b2, bias, (float*)d_out, n);
}

// Round 9
// 154.824 us; speedup vs baseline: 1.0832x; 1.0832x over previous
//
#include <hip/hip_runtime.h>
#include <math.h>

#define JT 64                // j per block
#define ITILE 1024           // i per block (4 per thread, 256 threads)
#define T8 8                 // 1024-tiles per dimension
#define NJOB_AB 1024         // 8 i-tiles * 128 j-chunks
#define NJOB_TRI 576         // 36 tri-tiles * 16 chunks
#define NBLK (NJOB_AB + 2 * NJOB_TRI)  // 2176
#define L2E 1.4426950408889634f

typedef float v2f __attribute__((ext_vector_type(2)));

// exp2(-x) in ONE instruction: neg folded into VOP3 input modifier.
__device__ inline float fexp2n(float x) {
  float r;
  asm("v_exp_f32 %0, -%1" : "=v"(r) : "v"(x));
  return r;
}
__device__ inline float fsqrt(float x) {
  float r;
  asm("v_sqrt_f32 %0, %1" : "=v"(r) : "v"(x));
  return r;
}

__device__ inline double wred_d(double v) {
#pragma unroll
  for (int o = 32; o > 0; o >>= 1) v += __shfl_down(v, o, 64);
  return v;
}

__device__ inline double bred(double v, double* sm) {
  v = wred_d(v);
  __syncthreads();
  if ((threadIdx.x & 63) == 0) sm[threadIdx.x >> 6] = v;
  __syncthreads();
  return sm[0] + sm[1] + sm[2] + sm[3];
}

// wave 0: reduce 64 prep slots -> smean[8] = {Sb,Qb,Mxb,Myb,St,Qt,Mxt,Myt}
__device__ inline void slot_reduce(const double* slot, double* smean) {
  if (threadIdx.x < 64) {
    int l = threadIdx.x;
    const double* sl = slot + l * 4;
#pragma unroll
    for (int c = 0; c < 4; ++c) {
      double v = sl[c];
      double vb = (l < 32) ? v : 0.0;
      double vt = (l < 32) ? 0.0 : v;
      vb = wred_d(vb);
      vt = wred_d(vt);
      if (l == 0) {
        smean[c] = vb;
        smean[4 + c] = vt;
      }
    }
  }
}

__global__ __launch_bounds__(256) void prep_kernel(
    const float* __restrict__ base, const float* __restrict__ target,
    const float* __restrict__ log_sigmas, const float* __restrict__ log_scale,
    const float* __restrict__ w1, const float* __restrict__ b1,
    const float* __restrict__ w2, const float* __restrict__ b2,
    float4* __restrict__ pxyu, double* __restrict__ slot,
    unsigned* __restrict__ fctr, int n) {
  __shared__ double sm[4];
  int gid = blockIdx.x * 256 + threadIdx.x;
  int isT = gid >= n;  // uniform per block (n % 256 == 0)
  const float* pts = isT ? target : base;
  int idx = isT ? gid - n : gid;
  float ex = __expf(log_scale[0]);
  float ey = __expf(log_scale[1]);
  float s2 = __expf(log_sigmas[2]);
  float r2 = __fsqrt_rn(L2E / (2.f * s2 * s2));  // coord pre-scale, band 2
  float2 p = ((const float2*)pts)[idx];
  float xr = p.x * ex, yr = p.y * ey;  // MLP input space (no r2!)
  float logit = b2[0];
#pragma unroll
  for (int k = 0; k < 32; ++k) {
    float h = fmaf(xr, w1[k], fmaf(yr, w1[32 + k], b1[k]));
    h = fmaxf(h, 0.f);
    logit = fmaf(h, w2[k], logit);
  }
  float u = fmaxf(logit, 0.f) + log1pf(__expf(-fabsf(logit))) + 1e-6f;
  float X = xr * r2, Y = yr * r2;
  float q = fmaf(X, X, Y * Y);  // |P|^2
  pxyu[gid] = make_float4(X, Y, q, u);
  double su = bred((double)u, sm);
  double qu = bred((double)u * (double)u, sm);
  double mx = bred((double)u * (double)X, sm);
  double my = bred((double)u * (double)Y, sm);
  if (threadIdx.x == 0) {
    double* s = slot + blockIdx.x * 4;
    s[0] = su;
    s[1] = qu;
    s[2] = mx;
    s[3] = my;
    if (blockIdx.x == 0) *fctr = 0u;
  }
}

// Inner loop: j loaded with wave-UNIFORM address from const __restrict__
// global -> compiler emits s_load into SGPRs (no LDS, no barrier, no VALU
// staging cost). pk-FP32 over two i-pairs per thread (4 i total).
template <bool AB, bool FAST>
__device__ inline void tile_loop(const float4* __restrict__ pJ4,
                                 const v2f xi2[2], const v2f yi2[2],
                                 const v2f Ai[2], const v2f al2[2], float cx2,
                                 float cy2, float rr0, float rr1, v2f a0[2],
                                 v2f a1[2], v2f a2[2], float& sdo,
                                 float& sqo) {
  v2f sd2 = {0.f, 0.f};
  v2f sq2 = {0.f, 0.f};
  const v2f vz = {0.f, 0.f};
#pragma unroll 4
  for (int j = 0; j < JT; ++j) {
    float4 J = pJ4[j];  // uniform addr -> s_load_dwordx4
    float xj = J.x, yj = J.y, qj = J.z, uj = J.w;
    float nbj;
    if constexpr (AB) nbj = -fmaf(cx2, xj, cy2 * yj);  // -beta_j
#pragma unroll
    for (int g = 0; g < 2; ++g) {
      v2f c = Ai[g] + qj;                    // pk_add (sgpr bcast)
      v2f pos = c - xi2[g] * xj - yi2[g] * yj;  // 2x pk_fma (neg mods)
      v2f k2 = {fexp2n(pos.x), fexp2n(pos.y)};
      v2f k0, k1;
      if constexpr (FAST) {
        v2f t = k2 * k2;
        k1 = t * t;  // k2^4  (sigma ratio 1:2)
        v2f t1 = k1 * k1;
        k0 = t1 * t1;  // k2^16 (sigma ratio 1:4)
      } else {
        v2f m1 = pos * rr1;
        v2f m0 = pos * rr0;
        k1 = {fexp2n(m1.x), fexp2n(m1.y)};
        k0 = {fexp2n(m0.x), fexp2n(m0.y)};
      }
      a0[g] += uj * k0;
      a1[g] += uj * k1;
      a2[g] += uj * k2;
      if constexpr (AB) {
        // uncentered scaled d2 = pos + al_i - beta_j; clamp vs cancellation
        v2f d2u = (pos + al2[g]) + nbj;
        d2u = __builtin_elementwise_max(d2u, vz);
        sq2 += d2u;
        v2f rt = {fsqrt(d2u.x), fsqrt(d2u.y)};
        sd2 += rt;
      }
    }
  }
  sdo = sd2.x + sd2.y;
  sqo = sq2.x + sq2.y;
}

__global__ __launch_bounds__(256) void pair_kernel(
    const float4* __restrict__ pxyu, const double* __restrict__ slot,
    double* __restrict__ paa, double* __restrict__ pbb,
    double* __restrict__ pab, double* __restrict__ psd,
    double* __restrict__ psq, unsigned* __restrict__ fctr,
    const float* __restrict__ log_sigmas, const float* __restrict__ g_w1,
    const float* __restrict__ g_b1, const float* __restrict__ g_w2,
    const float* __restrict__ g_b2, const float* __restrict__ bias,
    float* __restrict__ out, int n) {
  __shared__ double sm[4];
  __shared__ double smean[8];
  __shared__ int lastf;

  int b = blockIdx.x;
  int tid = threadIdx.x;
  int m, it, jt = 0, j0, pidx;
  if (b < NJOB_AB) {  // AB first (heavier), light tri jobs drain last
    m = 2;
    pidx = b;
    it = b >> 7;          // 8 i-tiles
    j0 = (b & 127) * JT;  // 128 j-chunks
  } else {
    int r = b - NJOB_AB;
    m = (r < NJOB_TRI) ? 0 : 1;
    if (m == 1) r -= NJOB_TRI;
    pidx = r;
    int tile = r >> 4;
    int q = r & 15;
    int idx = tile, len = T8;
    it = 0;
    while (idx >= len) {
      idx -= len;
      --len;
      ++it;
    }
    jt = it + idx;
    j0 = jt * ITILE + q * JT;
  }
  const float4* pI = pxyu + ((m == 1) ? n : 0);
  const float4* pJ = pxyu + ((m == 0) ? 0 : n);

  float cx = 0.f, cy = 0.f, cx2 = 0.f, cy2 = 0.f, cc = 0.f;
  if (m == 2) {
    slot_reduce(slot, smean);  // wave 0; consumed after the barrier below
  }

  float s0 = __expf(log_sigmas[0]);
  float s1 = __expf(log_sigmas[1]);
  float s2 = __expf(log_sigmas[2]);
  float rr0 = (s2 * s2) / (s0 * s0);
  float rr1 = (s2 * s2) / (s1 * s1);
  bool fast = (fabsf(rr0 - 16.f) <= 0.016f) && (fabsf(rr1 - 4.f) <= 0.004f);

  if (m == 2) {
    __syncthreads();
    cx = (float)(smean[2] / smean[0] - smean[6] / smean[4]);
    cy = (float)(smean[3] / smean[0] - smean[7] / smean[4]);
    cx2 = 2.f * cx;
    cy2 = 2.f * cy;
    cc = cx * cx + cy * cy;
  }

  int i0 = it * ITILE + tid;
  v2f xi2[2], yi2[2], Ai[2], al2[2];
  float u[4];
#pragma unroll
  for (int i = 0; i < 4; ++i) {
    float4 P = pI[i0 + i * 256];
    u[i] = P.w;
    float xv = P.x, yv = P.y, alv = 0.f;
    float Av;
    if (m == 2) {  // center i-side; alpha recovers uncentered distance
      xv -= cx;
      yv -= cy;
      alv = fmaf(cx2, xv, cy2 * yv) + cc;
      Av = fmaf(xv, xv, yv * yv);
    } else {
      Av = P.z;
    }
    int g = i >> 1, h = i & 1;
    xi2[g][h] = 2.f * xv;
    yi2[g][h] = 2.f * yv;
    Ai[g][h] = Av;
    al2[g][h] = alv;
  }

  v2f a0[2] = {}, a1[2] = {}, a2[2] = {};
  float sd = 0.f, sq = 0.f;
  const float4* pJ4 = pJ + j0;
  if (m == 2) {
    if (fast)
      tile_loop<true, true>(pJ4, xi2, yi2, Ai, al2, cx2, cy2, rr0, rr1, a0,
                            a1, a2, sd, sq);
    else
      tile_loop<true, false>(pJ4, xi2, yi2, Ai, al2, cx2, cy2, rr0, rr1, a0,
                             a1, a2, sd, sq);
  } else {
    if (fast)
      tile_loop<false, true>(pJ4, xi2, yi2, Ai, al2, cx2, cy2, rr0, rr1, a0,
                             a1, a2, sd, sq);
    else
      tile_loop<false, false>(pJ4, xi2, yi2, Ai, al2, cx2, cy2, rr0, rr1, a0,
                              a1, a2, sd, sq);
  }

  double wgt = (m != 2 && jt != it) ? 2.0 : 1.0;  // symmetric off-diag tiles
  double c0 = 0.0, c1 = 0.0, c2 = 0.0;
#pragma unroll
  for (int i = 0; i < 4; ++i) {
    int g = i >> 1, h = i & 1;
    c0 += (double)u[i] * (double)a0[g][h];
    c1 += (double)u[i] * (double)a1[g][h];
    c2 += (double)u[i] * (double)a2[g][h];
  }
  double r0 = bred(c0, sm) * wgt;
  double r1 = bred(c1, sm) * wgt;
  double r2d = bred(c2, sm) * wgt;
  double* prow = (m == 0) ? paa : (m == 1) ? pbb : pab;
  int stride = (m == 2) ? NJOB_AB : NJOB_TRI;
  if (tid == 0) {
    prow[0 * stride + pidx] = r0;
    prow[1 * stride + pidx] = r1;
    prow[2 * stride + pidx] = r2d;
  }
  if (m == 2) {
    double rsd = bred((double)sd, sm);
    double rsq = bred((double)sq, sm);
    if (tid == 0) {
      psd[pidx] = rsd;
      psq[pidx] = rsq;
    }
  }

  // ---- last-block final reduction (ticket + device fence) ----
  if (tid == 0) {
    __threadfence();
    unsigned old = atomicAdd(fctr, 1u);
    lastf = (old == NBLK - 1) ? 1 : 0;
  }
  __syncthreads();
  if (!lastf) return;
  __threadfence();

  slot_reduce(slot, smean);
  __syncthreads();
  int t = tid;
  double vaa[3], vbb[3], vab[3];
  for (int s = 0; s < 3; ++s) {
    const double* pa = paa + s * NJOB_TRI;
    const double* pb = pbb + s * NJOB_TRI;
    const double* pc = pab + s * NJOB_AB;
    double va = pa[t] + pa[t + 256] + ((t < 64) ? pa[t + 512] : 0.0);
    double vb = pb[t] + pb[t + 256] + ((t < 64) ? pb[t + 512] : 0.0);
    double vc = pc[t] + pc[t + 256] + pc[t + 512] + pc[t + 768];
    vaa[s] = bred(va, sm);
    vbb[s] = bred(vb, sm);
    vab[s] = bred(vc, sm);
  }
  double sdt = bred(psd[t] + psd[t + 256] + psd[t + 512] + psd[t + 768], sm);
  double sqt = bred(psq[t] + psq[t + 256] + psq[t + 512] + psq[t + 768], sm);

  if (tid == 0) {
    double Sb = smean[0], Qb = smean[1], St = smean[4], Qt = smean[5];
    double pband[3];
    for (int s = 0; s < 3; ++s)
      pband[s] = vaa[s] / (Sb * Sb) + vbb[s] / (St * St) -
                 2.0 * vab[s] / (Sb * St);
    double s2d = (double)s2;
    double r2sq = (double)L2E / (2.0 * s2d * s2d);
    double sd_real = sdt / sqrt(r2sq);
    double sq_real = sqt / r2sq;
    double NN = (double)n;
    double NM = NN * NN;
    double mean_d = sd_real / NM;
    double var_d = (sq_real - sd_real * sd_real / NM) / (NM - 1.0);
    double wv = (Qb / (Sb * Sb) - 1.0 / NN) / (NN - 1.0) +
                (Qt / (St * St) - 1.0 / NN) / (NN - 1.0);
    float st[4] = {(float)mean_d, (float)var_d, 0.f, (float)wv};
    float gl[3] = {g_b2[0], g_b2[1], g_b2[2]};
    for (int k = 0; k < 32; ++k) {
      float h = g_b1[k];
      for (int c = 0; c < 4; ++c) h = fmaf(st[c], g_w1[c * 32 + k], h);
      h = fmaxf(h, 0.f);
      for (int s = 0; s < 3; ++s) gl[s] = fmaf(h, g_w2[k * 3 + s], gl[s]);
    }
    float gw[3];
    float gsum = 0.f;
    for (int s = 0; s < 3; ++s) {
      gw[s] = fmaxf(gl[s], 0.f) + log1pf(__expf(-fabsf(gl[s])));
      gsum += gw[s];
    }
    double r = 0.0;
    for (int s = 0; s < 3; ++s) r += (double)(gw[s] / gsum) * pband[s];
    out[0] = (float)(r + (double)bias[0]);
  }
}

extern "C" void kernel_launch(void* const* d_in, const int* in_sizes, int n_in,
                              void* d_out, int out_size, void* d_ws,
                              size_t ws_size, hipStream_t stream) {
  const float* base = (const float*)d_in[0];
  const float* target = (const float*)d_in[1];
  const float* log_sigmas = (const float*)d_in[2];
  const float* log_scale = (const float*)d_in[3];
  const float* wn_w1 = (const float*)d_in[4];
  const float* wn_b1 = (const float*)d_in[5];
  const float* wn_w2 = (const float*)d_in[6];
  const float* wn_b2 = (const float*)d_in[7];
  const float* g_w1 = (const float*)d_in[8];
  const float* g_b1 = (const float*)d_in[9];
  const float* g_w2 = (const float*)d_in[10];
  const float* g_b2 = (const float*)d_in[11];
  const float* bias = (const float*)d_in[12];
  int n = in_sizes[0] / 2;  // 8192

  double* dbase = (double*)d_ws;
  double* slot = dbase;                // 64*4 = 256
  double* paa = dbase + 256;           // 3*576
  double* pbb = paa + 3 * NJOB_TRI;    // 3*576
  double* pab = pbb + 3 * NJOB_TRI;    // 3*1024
  double* psd = pab + 3 * NJOB_AB;     // 1024
  double* psq = psd + NJOB_AB;         // 1024
  double* dend = psq + NJOB_AB;        // 16B-aligned
  float4* pxyu = (float4*)dend;        // 2n
  unsigned* fctr = (unsigned*)(pxyu + 2 * n);

  prep_kernel<<<(2 * n) / 256, 256, 0, stream>>>(
      base, target, log_sigmas, log_scale, wn_w1, wn_b1, wn_w2, wn_b2, pxyu,
      slot, fctr, n);
  pair_kernel<<<NBLK, 256, 0, stream>>>(pxyu, slot, paa, pbb, pab, psd, psq,
                                        fctr, log_sigmas, g_w1, g_b1, g_w2,
                                        g_b2, bias, (float*)d_out, n);
}